// Round 8
// baseline (104.719 us; speedup 1.0000x reference)
//
#include <hip/hip_runtime.h>
#include <hip/hip_bf16.h>

typedef __bf16 bf16_t;
typedef bf16_t bf16x8 __attribute__((ext_vector_type(8)));
typedef bf16_t bf16x4 __attribute__((ext_vector_type(4)));
typedef float  floatx4 __attribute__((ext_vector_type(4)));

#define NROWS 65536
#define NDIM  128
#define BM    32
#define NBLKS (NROWS / BM)   // 2048 one-shot blocks
#define PITCH 136            // bf16 elems; 272-B row pitch, 16B-aligned

// d_ws: [0,131072) mu bf16 frag-major; [131072,133120) h2 = 0.5*|mu_bf16|^2 float[512]
// frag-major addr(col,k) = jg*2048 + kk*512 + quad*128 + l16*8 + e
//   col = jg*16 + l16, k = kk*32 + quad*8 + e
// -> B-frag b128 load is 1KB lane-contiguous per (jg,kk): perfectly coalesced L2 stream.

__global__ __launch_bounds__(256)
void mu_pack_kernel(const float* __restrict__ mu, bf16_t* __restrict__ ws_mu,
                    float* __restrict__ ws_h2)
{
    const int tid = threadIdx.x;
    const int col_local = tid >> 5;     // 8 cols per block
    const int j = tid & 31;             // 32 threads per col, 4 floats each
    const int col = blockIdx.x * 8 + col_local;
    const float4 v = *(const float4*)(mu + col * NDIM + j * 4);
    bf16x4 pk = {(bf16_t)v.x, (bf16_t)v.y, (bf16_t)v.z, (bf16_t)v.w};
    const int k0 = j * 4;
    const int kk = k0 >> 5, quad = (k0 >> 3) & 3, e0 = k0 & 7;
    const int jg = col >> 4, c16 = col & 15;
    *(bf16x4*)(ws_mu + jg*2048 + kk*512 + quad*128 + c16*8 + e0) = pk;
    float f0=(float)pk[0], f1=(float)pk[1], f2=(float)pk[2], f3=(float)pk[3];
    float s = f0*f0 + f1*f1 + f2*f2 + f3*f3;
    s += __shfl_xor(s, 1);  s += __shfl_xor(s, 2);  s += __shfl_xor(s, 4);
    s += __shfl_xor(s, 8);  s += __shfl_xor(s, 16);
    if (j == 0) ws_h2[col] = 0.5f * s;
}

// One-shot block: 32 rows x 512 cols. Wave w covers cols [w*128, w*128+128).
// ~115 VGPR target -> 4 waves/SIMD (16 waves/CU) under the 128-reg cap.
__global__ __launch_bounds__(256, 4)
void kmeans_main(const float* __restrict__ z, const bf16_t* __restrict__ ws_mu,
                 const float* __restrict__ ws_h2, float* __restrict__ out)
{
    __shared__ bf16_t ztile[BM * PITCH];   // 8704 B
    __shared__ float z2s[BM];              // 128 B
    __shared__ float rmx[4][BM];           // 512 B   -> ~9.4 KB total

    const int tid  = threadIdx.x;
    const int lane = tid & 63;
    const int w    = tid >> 6;
    const int quad = lane >> 4;
    const int l16  = lane & 15;
    const size_t rowbase = (size_t)blockIdx.x * BM;

    // ---- one-shot A stage: 16 consecutive floats per thread (wave = 4KB contig) ----
    {
        const int row = tid >> 3, seg = tid & 7;
        const float* rp = z + (rowbase + row) * NDIM + seg * 16;
        float4 a = *(const float4*)(rp);
        float4 b = *(const float4*)(rp + 4);
        float4 c = *(const float4*)(rp + 8);
        float4 d = *(const float4*)(rp + 12);
        bf16x8 p0 = {(bf16_t)a.x, (bf16_t)a.y, (bf16_t)a.z, (bf16_t)a.w,
                     (bf16_t)b.x, (bf16_t)b.y, (bf16_t)b.z, (bf16_t)b.w};
        bf16x8 p1 = {(bf16_t)c.x, (bf16_t)c.y, (bf16_t)c.z, (bf16_t)c.w,
                     (bf16_t)d.x, (bf16_t)d.y, (bf16_t)d.z, (bf16_t)d.w};
        *(bf16x8*)&ztile[row * PITCH + seg * 16]     = p0;
        *(bf16x8*)&ztile[row * PITCH + seg * 16 + 8] = p1;
        float ss = 0.f;
#pragma unroll
        for (int e = 0; e < 8; ++e) {
            float f0 = (float)p0[e], f1 = (float)p1[e];
            ss = fmaf(f0, f0, ss); ss = fmaf(f1, f1, ss);
        }
        ss += __shfl_xor(ss, 1); ss += __shfl_xor(ss, 2); ss += __shfl_xor(ss, 4);
        if ((lane & 7) == 0) z2s[row] = ss;   // one writer per row
    }
    __syncthreads();

    // ---- A frags from LDS (no-spill source): 32 regs ----
    bf16x8 afr[2][4];
#pragma unroll
    for (int i = 0; i < 2; ++i)
#pragma unroll
        for (int kk = 0; kk < 4; ++kk)
            afr[i][kk] = *(const bf16x8*)&ztile[(i*16 + l16) * PITCH + kk*32 + quad*8];

    // ---- B: stream 8 col-groups from packed L2, double-buffered (32 regs) ----
    const bf16_t* bbase  = ws_mu + (size_t)(w * 8) * 2048 + quad*128 + l16*8;
    const float*  h2base = ws_h2 + (w * 8) * 16 + l16;
    bf16x8 bb[2][4];
    float  h2b[2];
#pragma unroll
    for (int kk = 0; kk < 4; ++kk)
        bb[0][kk] = *(const bf16x8*)(bbase + kk*512);
    h2b[0] = h2base[0];

    float tm[2][4];
#pragma unroll
    for (int i = 0; i < 2; ++i)
#pragma unroll
        for (int r = 0; r < 4; ++r) tm[i][r] = -3.0e38f;

#pragma unroll 2
    for (int j = 0; j < 8; ++j) {
        const int cb = j & 1;
        if (j < 7) {
#pragma unroll
            for (int kk = 0; kk < 4; ++kk)
                bb[cb ^ 1][kk] = *(const bf16x8*)(bbase + (size_t)(j+1)*2048 + kk*512);
            h2b[cb ^ 1] = h2base[(j + 1) * 16];
        }
        const float mh = -h2b[cb];             // acc-init = -0.5*|mu_col|^2
#pragma unroll
        for (int i = 0; i < 2; ++i) {
            floatx4 acc = (floatx4){mh, mh, mh, mh};
#pragma unroll
            for (int kk = 0; kk < 4; ++kk)
                acc = __builtin_amdgcn_mfma_f32_16x16x32_bf16(
                    afr[i][kk], bb[cb][kk], acc, 0, 0, 0);
#pragma unroll
            for (int r = 0; r < 4; ++r)
                tm[i][r] = fmaxf(tm[i][r], acc[r]);   // deferred sqrt
        }
    }

    // ---- per-row max over this wave's 128 cols, publish per wave ----
#pragma unroll
    for (int i = 0; i < 2; ++i)
#pragma unroll
        for (int r = 0; r < 4; ++r) {
            float v = tm[i][r];
            v = fmaxf(v, __shfl_xor(v, 1));
            v = fmaxf(v, __shfl_xor(v, 2));
            v = fmaxf(v, __shfl_xor(v, 4));
            v = fmaxf(v, __shfl_xor(v, 8));
            if (l16 == 0) rmx[w][i*16 + quad*4 + r] = v;
        }
    __syncthreads();

    // ---- wave 0: sqrt per row, reduce, one atomic per block ----
    float sv = 0.f;
    if (tid < BM) {
        float m = fmaxf(fmaxf(rmx[0][tid], rmx[1][tid]),
                        fmaxf(rmx[2][tid], rmx[3][tid]));
        float d2 = z2s[tid] - 2.0f * m;
        sv = sqrtf(fmaxf(d2, 0.f));
    }
    if (w == 0) {
#pragma unroll
        for (int off = 32; off; off >>= 1) sv += __shfl_down(sv, off);
        if (tid == 0) atomicAdd(out, sv * (1.0f / 65536.0f));
    }
}

extern "C" void kernel_launch(void* const* d_in, const int* in_sizes, int n_in,
                              void* d_out, int out_size, void* d_ws, size_t ws_size,
                              hipStream_t stream) {
    const float* z  = (const float*)d_in[0];
    const float* mu = (const float*)d_in[1];
    float* out = (float*)d_out;
    bf16_t* ws_mu = (bf16_t*)d_ws;
    float* ws_h2 = (float*)((char*)d_ws + 131072);
    hipMemsetAsync(out, 0, sizeof(float), stream);   // d_out poisoned 0xAA
    mu_pack_kernel<<<dim3(64), dim3(256), 0, stream>>>(mu, ws_mu, ws_h2);
    kmeans_main<<<dim3(NBLKS), dim3(256), 0, stream>>>(z, ws_mu, ws_h2, out);
}